// Round 1
// baseline (1982.695 us; speedup 1.0000x reference)
//
#include <hip/hip_runtime.h>
#include <hip/hip_bf16.h>

// Problem: out = kv_buffer; out[loc] = concat(cache_k_nope, cache_k_rope)
//   kv_buffer:    [524288, 576] fp32  (d_in[0])
//   loc:          [32768]       int32 (d_in[1])  (unique indices)
//   cache_k_nope: [32768, 512]  fp32  (d_in[2])
//   cache_k_rope: [32768, 64]   fp32  (d_in[3])
//
// R6 = R5b (thread-per-float4 fused pass + nontemporal streaming, 1830 us
// total) restructured for memory-level parallelism:
//   - 4-way grid-stride per thread (coalescing preserved: lanes stay
//     contiguous within each pass; R3's regression was consecutive-per-
//     thread mapping, which this is not).
//   - all 4 mark[] loads issued before any data load (the mark->data
//     serial chain was the suspected limiter vs. pure-copy rate).
//   - branchless address select (cndmask on pointer) instead of a
//     divergent two-sided load.
// Mandatory traffic 2.416 GB -> ~385-440 us floor for the fused dispatch.
// History: R3 (4xfloat4 consecutive/thread) broke coalescing, +105 us.
// R4 (wave-per-row) scalar-load dependency + tail store, +96 us.

#define BUF_SLOTS 524288
#define N_LOC     32768
#define ROW_V     144           // float4 per row
#define NOPE_V    128           // float4 per row of nope
#define ROPE_V    16            // float4 per row of rope

#define TOTAL_V   (BUF_SLOTS * ROW_V)      // 75,497,472 float4
#define ITER      4
#define STRIDE_V  (TOTAL_V / ITER)         // 18,874,368 (exact)
#define FUSED_GRID (STRIDE_V / 256)        // 73,728 blocks, no tail

typedef float vf4 __attribute__((ext_vector_type(4)));

__device__ __forceinline__ vf4 ntload(const vf4* __restrict__ p) {
    return __builtin_nontemporal_load(p);
}
__device__ __forceinline__ void ntstore(vf4* __restrict__ p, vf4 v) {
    __builtin_nontemporal_store(v, p);
}

__global__ __launch_bounds__(256) void init_mark(int* __restrict__ mark)
{
    const int tid = blockIdx.x * 256 + threadIdx.x;
    if (tid < BUF_SLOTS) mark[tid] = -1;
}

__global__ __launch_bounds__(256) void build_mark(const int* __restrict__ loc,
                                                  int* __restrict__ mark)
{
    const int tid = blockIdx.x * 256 + threadIdx.x;
    if (tid < N_LOC) mark[loc[tid]] = tid;
}

// 4 float4 per thread, grid-strided. Marks prefetched as a batch, data
// loads branchless-address-selected, stores last.
__global__ __launch_bounds__(256) void fused_write(
    const vf4* __restrict__ kv,
    const vf4* __restrict__ nope,
    const vf4* __restrict__ rope,
    const int* __restrict__ mark,
    vf4*       __restrict__ out)
{
    const unsigned base = blockIdx.x * 256u + threadIdx.x;

    unsigned t[ITER], row[ITER], j[ITER];
    int      m[ITER];
#pragma unroll
    for (int i = 0; i < ITER; ++i) {
        t[i]   = base + (unsigned)i * (unsigned)STRIDE_V;
        row[i] = t[i] / ROW_V;                 // magic-mul division
        j[i]   = t[i] - row[i] * ROW_V;
        m[i]   = mark[row[i]];                 // 4 independent L2 loads
    }

    vf4 v[ITER];
#pragma unroll
    for (int i = 0; i < ITER; ++i) {
        const vf4* p = &kv[t[i]];
        if (m[i] >= 0) {
            const unsigned mm = (unsigned)m[i];
            p = (j[i] < NOPE_V) ? &nope[mm * NOPE_V + j[i]]
                                : &rope[mm * ROPE_V + (j[i] - NOPE_V)];
        }
        v[i] = ntload(p);                      // 4 independent HBM loads
    }

#pragma unroll
    for (int i = 0; i < ITER; ++i) {
        ntstore(&out[t[i]], v[i]);
    }
}

// Fallback path (ws too small): plain copy + scatter.
__global__ __launch_bounds__(256) void copy_buf(const vf4* __restrict__ src,
                                                vf4* __restrict__ dst)
{
    const int t = blockIdx.x * 256 + threadIdx.x;
    ntstore(&dst[t], ntload(&src[t]));
}

__global__ __launch_bounds__(256) void scatter_rows(
    const int* __restrict__ loc,
    const vf4* __restrict__ nope,
    const vf4* __restrict__ rope,
    vf4*       __restrict__ out)
{
    const int tid = blockIdx.x * 256 + threadIdx.x;
    const int n_nope = N_LOC * NOPE_V;   // multiple of 256
    if (tid < n_nope) {
        const int token = tid >> 7;
        const int j     = tid & (NOPE_V - 1);
        const int r     = loc[token];
        out[(size_t)r * ROW_V + j] = nope[(size_t)token * NOPE_V + j];
    } else {
        const int t2    = tid - n_nope;
        const int token = t2 >> 4;
        const int j     = t2 & (ROPE_V - 1);
        const int r     = loc[token];
        out[(size_t)r * ROW_V + NOPE_V + j] = rope[(size_t)token * ROPE_V + j];
    }
}

extern "C" void kernel_launch(void* const* d_in, const int* in_sizes, int n_in,
                              void* d_out, int out_size, void* d_ws, size_t ws_size,
                              hipStream_t stream)
{
    const vf4* kv   = (const vf4*)d_in[0];
    const int* loc  = (const int*)d_in[1];
    const vf4* nope = (const vf4*)d_in[2];
    const vf4* rope = (const vf4*)d_in[3];
    vf4*       out  = (vf4*)d_out;

    if (ws_size >= (size_t)BUF_SLOTS * sizeof(int)) {
        int* mark = (int*)d_ws;
        init_mark<<<BUF_SLOTS / 256, 256, 0, stream>>>(mark);
        build_mark<<<N_LOC / 256, 256, 0, stream>>>(loc, mark);
        fused_write<<<FUSED_GRID, 256, 0, stream>>>(kv, nope, rope, mark, out);
    } else {
        const int total = BUF_SLOTS * ROW_V;
        copy_buf<<<total / 256, 256, 0, stream>>>(kv, out);
        const int sthreads = N_LOC * (NOPE_V + ROPE_V);
        scatter_rows<<<sthreads / 256, 256, 0, stream>>>(loc, nope, rope, out);
    }
}

// Round 2
// 1851.920 us; speedup vs baseline: 1.0706x; 1.0706x over previous
//
#include <hip/hip_runtime.h>
#include <hip/hip_bf16.h>

// Problem: out = kv_buffer; out[loc] = concat(cache_k_nope, cache_k_rope)
//   kv_buffer:    [524288, 576] fp32  (d_in[0])
//   loc:          [32768]       int32 (d_in[1])  (unique indices)
//   cache_k_nope: [32768, 512]  fp32  (d_in[2])
//   cache_k_rope: [32768, 64]   fp32  (d_in[3])
//
// R7: A/B experiment — drop the fused mark-based kernel; run the pure
// streaming pair instead:
//   copy_buf:     out <- kv_buffer  (1.208 GB R + 1.208 GB W, zero
//                 data-dependent addressing; rocclr fill proves this
//                 pattern sustains 6.2-6.3 TB/s)
//   scatter_rows: out[loc[i]] <- concat(nope[i], rope[i])  (144 MB)
// Traffic 2.56 GB (+6% vs fused 2.416 GB) but no per-element mark load,
// no divergent source select, 2 dispatches instead of 3.
// Opposite-prediction test: if fused was BW-bound at min traffic this is
// ~+25 us (then R5b = roofline); if the mark chain cost streaming rate,
// this is -70..-150 us.
// History: R3 (4xfloat4 consecutive/thread) +105 us. R4 (wave-per-row)
// +96 us. R6 (4-way grid-stride MLP batch) +153 us — all per-thread-work
// increases regress; thread-per-float4 is the right shape.

#define BUF_SLOTS 524288
#define N_LOC     32768
#define ROW_V     144           // float4 per row
#define NOPE_V    128           // float4 per row of nope
#define ROPE_V    16            // float4 per row of rope

typedef float vf4 __attribute__((ext_vector_type(4)));

__device__ __forceinline__ vf4 ntload(const vf4* __restrict__ p) {
    return __builtin_nontemporal_load(p);
}
__device__ __forceinline__ void ntstore(vf4* __restrict__ p, vf4 v) {
    __builtin_nontemporal_store(v, p);
}

// Pure streaming copy: thread per float4. Same shape as the rocclr fill
// kernel that sustains 6.2+ TB/s.
__global__ __launch_bounds__(256) void copy_buf(const vf4* __restrict__ src,
                                                vf4* __restrict__ dst)
{
    const int t = blockIdx.x * 256 + threadIdx.x;
    ntstore(&dst[t], ntload(&src[t]));
}

// Scatter the 32768 updated rows. Thread per float4 of the update set.
// loc[] reads are wave-uniform-ish (16..128 lanes share a token) and
// L1/L2 cached; writes are contiguous 2304 B row chunks.
__global__ __launch_bounds__(256) void scatter_rows(
    const int* __restrict__ loc,
    const vf4* __restrict__ nope,
    const vf4* __restrict__ rope,
    vf4*       __restrict__ out)
{
    const int tid = blockIdx.x * 256 + threadIdx.x;
    const int n_nope = N_LOC * NOPE_V;   // 4,194,304, multiple of 256
    if (tid < n_nope) {
        const int token = tid >> 7;
        const int j     = tid & (NOPE_V - 1);
        const int r     = loc[token];
        ntstore(&out[(size_t)r * ROW_V + j],
                ntload(&nope[(size_t)token * NOPE_V + j]));
    } else {
        const int t2    = tid - n_nope;
        const int token = t2 >> 4;
        const int j     = t2 & (ROPE_V - 1);
        const int r     = loc[token];
        ntstore(&out[(size_t)r * ROW_V + NOPE_V + j],
                ntload(&rope[(size_t)token * ROPE_V + j]));
    }
}

extern "C" void kernel_launch(void* const* d_in, const int* in_sizes, int n_in,
                              void* d_out, int out_size, void* d_ws, size_t ws_size,
                              hipStream_t stream)
{
    const vf4* kv   = (const vf4*)d_in[0];
    const int* loc  = (const int*)d_in[1];
    const vf4* nope = (const vf4*)d_in[2];
    const vf4* rope = (const vf4*)d_in[3];
    vf4*       out  = (vf4*)d_out;

    const int total = BUF_SLOTS * ROW_V;          // 75,497,472
    copy_buf<<<total / 256, 256, 0, stream>>>(kv, out);

    const int sthreads = N_LOC * (NOPE_V + ROPE_V);   // 4,718,592
    scatter_rows<<<sthreads / 256, 256, 0, stream>>>(loc, nope, rope, out);
}

// Round 3
// 1820.382 us; speedup vs baseline: 1.0892x; 1.0173x over previous
//
#include <hip/hip_runtime.h>
#include <hip/hip_bf16.h>

// Problem: out = kv_buffer; out[loc] = concat(cache_k_nope, cache_k_rope)
//   kv_buffer:    [524288, 576] fp32  (d_in[0])
//   loc:          [32768]       int32 (d_in[1])  (unique indices)
//   cache_k_nope: [32768, 512]  fp32  (d_in[2])
//   cache_k_rope: [32768, 64]   fp32  (d_in[3])
//
// R8 = revert to R5b, the best-measured kernel (1821-1830 us total).
// Roofline case closed by A/B:
//   - R7 (pure copy+scatter, +6% traffic, zero data-dependent addressing)
//     came in at exactly +22 us = Delta_bytes / 6.3 TB/s -> the fused pass
//     is BW-bound at MINIMUM traffic (2.416 GB); mark[] load + source
//     select hide fully under the HBM stream (144x L2 reuse per mark line).
//   - R3 (4x consecutive/thread) +105, R4 (wave-per-row) +96,
//     R6 (4x grid-stride MLP batch) +153: every per-thread-work increase
//     regresses; thread-per-float4 is the right shape.
// Controllable floor: 2.416 GB / 6.29 TB/s ~= 385 us. Remaining ~1400 us
// of the total is harness-fixed poison/restore traffic (the ~775 us
// rocclr fills dominating every top-5).

#define BUF_SLOTS 524288
#define N_LOC     32768
#define ROW_V     144           // float4 per row
#define NOPE_V    128           // float4 per row of nope
#define ROPE_V    16            // float4 per row of rope

typedef float vf4 __attribute__((ext_vector_type(4)));

__device__ __forceinline__ vf4 ntload(const vf4* __restrict__ p) {
    return __builtin_nontemporal_load(p);
}
__device__ __forceinline__ void ntstore(vf4* __restrict__ p, vf4 v) {
    __builtin_nontemporal_store(v, p);
}

__global__ __launch_bounds__(256) void init_mark(int* __restrict__ mark)
{
    const int tid = blockIdx.x * 256 + threadIdx.x;
    if (tid < BUF_SLOTS) mark[tid] = -1;
}

__global__ __launch_bounds__(256) void build_mark(const int* __restrict__ loc,
                                                  int* __restrict__ mark)
{
    const int tid = blockIdx.x * 256 + threadIdx.x;
    if (tid < N_LOC) mark[loc[tid]] = tid;
}

// One thread per output float4. t = row*144 + j.
__global__ __launch_bounds__(256) void fused_write(
    const vf4* __restrict__ kv,
    const vf4* __restrict__ nope,
    const vf4* __restrict__ rope,
    const int* __restrict__ mark,
    vf4*       __restrict__ out)
{
    const int t   = blockIdx.x * 256 + threadIdx.x;   // < 75,497,472, fits int
    const int row = t / ROW_V;                        // magic-mul division
    const int j   = t - row * ROW_V;
    const int m   = mark[row];                        // cached, 144x reuse
    vf4 v;
    if (m < 0) {
        v = ntload(&kv[t]);
    } else {
        v = (j < NOPE_V) ? ntload(&nope[m * NOPE_V + j])
                         : ntload(&rope[m * ROPE_V + (j - NOPE_V)]);
    }
    ntstore(&out[t], v);
}

// Fallback path (ws too small): plain copy + scatter.
__global__ __launch_bounds__(256) void copy_buf(const vf4* __restrict__ src,
                                                vf4* __restrict__ dst)
{
    const int t = blockIdx.x * 256 + threadIdx.x;
    ntstore(&dst[t], ntload(&src[t]));
}

__global__ __launch_bounds__(256) void scatter_rows(
    const int* __restrict__ loc,
    const vf4* __restrict__ nope,
    const vf4* __restrict__ rope,
    vf4*       __restrict__ out)
{
    const int tid = blockIdx.x * 256 + threadIdx.x;
    const int n_nope = N_LOC * NOPE_V;   // multiple of 256
    if (tid < n_nope) {
        const int token = tid >> 7;
        const int j     = tid & (NOPE_V - 1);
        const int r     = loc[token];
        out[(size_t)r * ROW_V + j] = nope[(size_t)token * NOPE_V + j];
    } else {
        const int t2    = tid - n_nope;
        const int token = t2 >> 4;
        const int j     = t2 & (ROPE_V - 1);
        const int r     = loc[token];
        out[(size_t)r * ROW_V + NOPE_V + j] = rope[(size_t)token * ROPE_V + j];
    }
}

extern "C" void kernel_launch(void* const* d_in, const int* in_sizes, int n_in,
                              void* d_out, int out_size, void* d_ws, size_t ws_size,
                              hipStream_t stream)
{
    const vf4* kv   = (const vf4*)d_in[0];
    const int* loc  = (const int*)d_in[1];
    const vf4* nope = (const vf4*)d_in[2];
    const vf4* rope = (const vf4*)d_in[3];
    vf4*       out  = (vf4*)d_out;

    if (ws_size >= (size_t)BUF_SLOTS * sizeof(int)) {
        int* mark = (int*)d_ws;
        init_mark<<<BUF_SLOTS / 256, 256, 0, stream>>>(mark);
        build_mark<<<N_LOC / 256, 256, 0, stream>>>(loc, mark);
        const int total = BUF_SLOTS * ROW_V;              // 75,497,472
        fused_write<<<total / 256, 256, 0, stream>>>(kv, nope, rope, mark, out);
    } else {
        const int total = BUF_SLOTS * ROW_V;
        copy_buf<<<total / 256, 256, 0, stream>>>(kv, out);
        const int sthreads = N_LOC * (NOPE_V + ROPE_V);
        scatter_rows<<<sthreads / 256, 256, 0, stream>>>(loc, nope, rope, out);
    }
}